// Round 4
// baseline (99.036 us; speedup 1.0000x reference)
//
#include <hip/hip_runtime.h>

// EmbeddingBag(mode='sum') + bias — v5: deep MLP + SGPR row indices +
// nontemporal streaming for output/index traffic.
// inputs: feature_indices [BATCH*BAG] int32, offsets [BATCH] int32,
//         table [6144,256] fp32, bias [256] fp32
// output: [BATCH, 256] fp32
//
// Roofline: the gather moves ~503 MB of table rows (491520 x 1KB) through
// L1/L2/L3 (table = 6 MB, L3-resident; HBM traffic only ~24 MB). Floor at
// aggregate L2 return BW (~34.5 TB/s) ~= 15 us. Measured baseline 99.3 us
// = 5.1 TB/s effective -> LATENCY-bound, ~7x headroom.
//
// Structure (unchanged from v4 — unmeasured due to broker outages):
//  - one wave per bag; lane owns 4 hidden dims (float4 -> each row read is
//    ONE contiguous 1KB coalesced wave load, 16B/lane).
//  - bag pinned to SGPR (readfirstlane; uniform by construction tid>>6) ->
//    scalar loop control and scalar store base.
//  - bag indices fetched ONCE per 64 in a single lane-parallel coalesced
//    load; each row's index broadcast to SGPR with v_readlane_b32 (uniform
//    selector) -> row loads are saddr-form (scalar base + hoisted lane*16
//    voffset): ~1 VALU + 2 SALU per row. No ds_bpermute, no per-row index
//    VMEM loads.
//  - CHUNK=16 rows issue back-to-back into independent VGPRs before any
//    accumulation: ONE memory phase per chunk, ~16 KB in flight per wave;
//    a 30-element bag = exactly 2 memory round trips.
//  - tail chunk runs at FULL depth: selector clamped, dummy rows weighted
//    0.0 via FMA -> no serial remainder.
//  - __launch_bounds__(256,4): VGPR cap 128 (est ~90) -> 4 waves/EU,
//    16 waves/CU -> up to 256 KB of row loads in flight per CU (floor
//    needs only ~16 KB/CU at ~280cy latency x 56 B/cy/CU).
//
// New in v5: output stores + index loads are NONTEMPORAL. The 16 MB output
// stream write-allocates in L2 and evicts the (reused, over-capacity:
// 6 MB table vs 4 MiB/XCD) table lines; nt keeps streaming traffic from
// displacing the 80x-reused table -> higher TCC_HIT on the gather path.

#define CHUNK 16

__global__ __launch_bounds__(256, 4) void embag_sum_kernel(
    const int* __restrict__ idx,
    const int* __restrict__ offsets,
    const float* __restrict__ table,
    const float* __restrict__ bias,
    float* __restrict__ out,
    int n_total, int batch) {
  // Wave-uniform bag id, pinned scalar.
  const int bag =
      __builtin_amdgcn_readfirstlane((int)((blockIdx.x * blockDim.x + threadIdx.x) >> 6));
  const int lane = (int)(threadIdx.x & 63);
  if (bag >= batch) return;

  const int start = offsets[bag];                                   // scalar
  const int end   = (bag + 1 < batch) ? offsets[bag + 1] : n_total; // scalar
  const int cnt   = end - start;

  const int h4 = lane * 4;  // this lane's 4 hidden dims
  float4 acc = *(const float4*)(bias + h4);

  // Rounds of <=64 indices: ONE lane-parallel coalesced index load each.
  // (cnt==30 here -> single round.)
  for (int base = 0; base < cnt; base += 64) {
    const int rcnt = min(64, cnt - base);                 // scalar
    // Single-use stream: nontemporal so it doesn't displace table lines.
    const int my = (lane < rcnt)
        ? __builtin_nontemporal_load(idx + start + base + lane) : 0;

    for (int k0 = 0; k0 < rcnt; k0 += CHUNK) {
      if (k0 + CHUNK <= rcnt) {
        // Full chunk: 16 independent 1KB row loads in flight, then add.
        float4 v[CHUNK];
#pragma unroll
        for (int j = 0; j < CHUNK; ++j) {
          const int r = __builtin_amdgcn_readlane(my, k0 + j);  // SGPR
          v[j] = *(const float4*)(table + (size_t)r * 256 + h4);
        }
#pragma unroll
        for (int j = 0; j < CHUNK; ++j) {
          acc.x += v[j].x; acc.y += v[j].y;
          acc.z += v[j].z; acc.w += v[j].w;
        }
      } else {
        // Tail chunk at full depth: selector clamped to lane 0 (always
        // valid), dummy rows weighted 0.0.
        float4 v[CHUNK];
        float  w[CHUNK];
#pragma unroll
        for (int j = 0; j < CHUNK; ++j) {
          const int kk    = k0 + j;
          const int ksafe = (kk < rcnt) ? kk : 0;               // scalar
          const int r = __builtin_amdgcn_readlane(my, ksafe);   // SGPR
          w[j] = (kk < rcnt) ? 1.0f : 0.0f;
          v[j] = *(const float4*)(table + (size_t)r * 256 + h4);
        }
#pragma unroll
        for (int j = 0; j < CHUNK; ++j) {
          acc.x = fmaf(w[j], v[j].x, acc.x);
          acc.y = fmaf(w[j], v[j].y, acc.y);
          acc.z = fmaf(w[j], v[j].z, acc.z);
          acc.w = fmaf(w[j], v[j].w, acc.w);
        }
      }
    }
  }

  // Streaming output: nontemporal store, one contiguous 1KB per wave.
  float* o = out + (size_t)bag * 256 + h4;
  __builtin_nontemporal_store(acc.x, o + 0);
  __builtin_nontemporal_store(acc.y, o + 1);
  __builtin_nontemporal_store(acc.z, o + 2);
  __builtin_nontemporal_store(acc.w, o + 3);
}

extern "C" void kernel_launch(void* const* d_in, const int* in_sizes, int n_in,
                              void* d_out, int out_size, void* d_ws, size_t ws_size,
                              hipStream_t stream) {
  const int*   idx     = (const int*)d_in[0];
  const int*   offsets = (const int*)d_in[1];
  const float* table   = (const float*)d_in[2];
  const float* bias    = (const float*)d_in[3];
  float*       out     = (float*)d_out;

  const int n_total = in_sizes[0];   // BATCH*BAG = 491520
  const int batch   = in_sizes[1];   // 16384

  // one wave per bag, 4 waves (256 threads) per block
  const int waves_per_block = 4;
  const int grid = (batch + waves_per_block - 1) / waves_per_block;
  embag_sum_kernel<<<grid, 256, 0, stream>>>(idx, offsets, table, bias, out,
                                             n_total, batch);
}